// Round 1
// baseline (1517.678 us; speedup 1.0000x reference)
//
#include <hip/hip_runtime.h>

typedef short bf16x8 __attribute__((ext_vector_type(8)));
typedef float f32x4 __attribute__((ext_vector_type(4)));

#define MFMA16(a, b, c) __builtin_amdgcn_mfma_f32_16x16x32_bf16(a, b, c, 0, 0, 0)

__device__ __forceinline__ short f2bf(float x) {
  unsigned u = __builtin_bit_cast(unsigned, x);
  u += 0x7fffu + ((u >> 16) & 1u);
  return (short)(u >> 16);
}

// ---- problem constants ----
#define BB 16
#define SS 4096
#define CC 640
#define TT 77
#define NHH 8
#define HDD 80
#define DP 96          // padded head-dim / padded T for attention K-loops
#define MM (BB * SS)   // 65536

// ================= K0a: weight transpose + bf16 convert =================
// wqT[i][c] <- wq[c][i];  woT[c][i] <- wo[i][c]  (both 640x640)
__global__ __launch_bounds__(256) void k_wt(const float* __restrict__ wq,
                                            const float* __restrict__ wo,
                                            short* __restrict__ wqT,
                                            short* __restrict__ woT) {
  const float* src = blockIdx.z ? wo : wq;
  short* dst = blockIdx.z ? woT : wqT;
  int o0 = blockIdx.x * 64;  // out-row dim (i for wqT, c for woT)
  int r0 = blockIdx.y * 64;  // src-row dim
  __shared__ float t[64][65];
  int tx = threadIdx.x & 63, ty = threadIdx.x >> 6;
#pragma unroll
  for (int it = 0; it < 16; ++it) {
    int rr = it * 4 + ty;
    t[tx][rr] = src[(size_t)(r0 + rr) * 640 + o0 + tx];
  }
  __syncthreads();
#pragma unroll
  for (int it = 0; it < 16; ++it) {
    int orow = it * 4 + ty;
    dst[(size_t)(o0 + orow) * 640 + r0 + tx] = f2bf(t[orow][tx]);
  }
}

// ================= K0b: LayerNorm stats =================
// block: 32 s-values of one b.  grid 2048 = 16 * 128
__global__ __launch_bounds__(256) void k_stats(const float* __restrict__ hs,
                                               float* __restrict__ muA,
                                               float* __restrict__ rsA) {
  int blk = blockIdx.x;
  int b = blk >> 7;
  int s0 = (blk & 127) * 32;
  __shared__ float red[2][8][32];
  int tid = threadIdx.x;
  int sl = tid & 31;
  int cg = tid >> 5;  // 0..7
  const float* base = hs + (size_t)b * CC * SS + s0 + sl;
  float sum = 0.f, sq = 0.f;
  for (int i = 0; i < 80; ++i) {
    int c = cg * 80 + i;
    float v = base[(size_t)c * SS];
    sum += v;
    sq += v * v;
  }
  red[0][cg][sl] = sum;
  red[1][cg][sl] = sq;
  __syncthreads();
  if (tid < 32) {
    float s = 0.f, q = 0.f;
#pragma unroll
    for (int g = 0; g < 8; ++g) { s += red[0][g][tid]; q += red[1][g][tid]; }
    float mu = s * (1.f / 640.f);
    float var = q * (1.f / 640.f) - mu * mu;
    int m = b * SS + s0 + tid;
    muA[m] = mu;
    rsA[m] = rsqrtf(var + 1e-6f);
  }
}

// ================= K0c: K/V projection =================
// grid (4 nq, 2 kv, 16 b), block 320 (5 waves; wave = t-tile)
// kb[b][h][t(80)][d(96)] = (enc @ wk)[t, h*80+d] * (1/sqrt(80))   (t>=77 rows = 0; d>=80 via memset)
// vb[b][h][d(80)][t(96)] = (enc @ wv)[t, h*80+d]                  (t>=77 cols via compute-zero/memset)
__global__ __launch_bounds__(320) void k_kv(const float* __restrict__ enc,
                                            const float* __restrict__ wk,
                                            const float* __restrict__ wv,
                                            short* __restrict__ kb,
                                            short* __restrict__ vb) {
  int nq = blockIdx.x, kv = blockIdx.y, b = blockIdx.z;
  const float* w = kv ? wv : wk;
  int n0 = nq * 160;
  int wave = threadIdx.x >> 6, lane = threadIdx.x & 63;
  int col = lane & 15, quad = lane >> 4, kq = quad * 8;
  __shared__ short bT[160][40];
  f32x4 acc[10] = {};
  int t = wave * 16 + col;
  bool tv = (t < TT);
  const float* arow = enc + ((size_t)b * TT + (tv ? t : 0)) * 768;
  for (int x0 = 0; x0 < 768; x0 += 32) {
    __syncthreads();
    for (int idx = threadIdx.x; idx < 160 * 32; idx += 320) {
      int cc = idx % 160;
      int xx = idx / 160;
      bT[cc][xx] = f2bf(w[(size_t)(x0 + xx) * 640 + n0 + cc]);
    }
    __syncthreads();
    bf16x8 af = {};
    if (tv) {
      const float* ap = arow + x0 + kq;
      float4 a0 = *(const float4*)ap;
      float4 a1 = *(const float4*)(ap + 4);
      af[0] = f2bf(a0.x); af[1] = f2bf(a0.y); af[2] = f2bf(a0.z); af[3] = f2bf(a0.w);
      af[4] = f2bf(a1.x); af[5] = f2bf(a1.y); af[6] = f2bf(a1.z); af[7] = f2bf(a1.w);
    }
#pragma unroll
    for (int nt = 0; nt < 10; ++nt) {
      bf16x8 bw = *(const bf16x8*)&bT[nt * 16 + col][kq];
      acc[nt] = MFMA16(af, bw, acc[nt]);
    }
  }
  float scale = kv ? 1.f : 0.11180339887498949f;
#pragma unroll
  for (int nt = 0; nt < 10; ++nt) {
    int i = n0 + nt * 16 + col;
    int h = i / 80, d = i % 80;
#pragma unroll
    for (int r = 0; r < 4; ++r) {
      int trow = wave * 16 + quad * 4 + r;  // 0..79 (77..79 compute as 0)
      float v = acc[nt][r] * scale;
      if (kv)
        vb[(((size_t)(b * NHH + h) * 80 + d) * DP) + trow] = f2bf(v);
      else
        kb[(((size_t)(b * NHH + h) * 80 + trow) * DP) + d] = f2bf(v);
    }
  }
}

// ================= K1: LayerNorm + Q projection GEMM =================
// grid (2 n-halves, 1024 m-blocks of 64), block 512 (8 waves: wave = (mt 0..3, nh 0..1))
__global__ __launch_bounds__(512) void k_qgemm(const float* __restrict__ hs,
                                               const float* __restrict__ muA,
                                               const float* __restrict__ rsA,
                                               const float* __restrict__ lnw,
                                               const float* __restrict__ lnb,
                                               const short* __restrict__ wqT,
                                               short* __restrict__ q) {
  int m0 = blockIdx.y * 64;
  int b = blockIdx.y >> 6;
  int s0 = (blockIdx.y & 63) * 64;
  int wave = threadIdx.x >> 6, lane = threadIdx.x & 63;
  int col = lane & 15, quad = lane >> 4, kq = quad * 8;
  int mt = wave & 3, nh = wave >> 2;
  int n0 = blockIdx.x * 320 + nh * 160;
  __shared__ short xA[64][40];
  int sl = threadIdx.x & 63;
  int cg = threadIdx.x >> 6;  // 0..7
  float mu = muA[m0 + sl];
  float rs = rsA[m0 + sl];
  const float* hsbase = hs + (size_t)b * CC * SS + s0 + sl;
  f32x4 acc[10] = {};
  for (int k0 = 0; k0 < 640; k0 += 32) {
    __syncthreads();
#pragma unroll
    for (int j = 0; j < 4; ++j) {
      int cc = cg + j * 8;
      int c = k0 + cc;
      float v = hsbase[(size_t)c * SS];
      xA[sl][cc] = f2bf((v - mu) * rs * lnw[c] + lnb[c]);
    }
    __syncthreads();
    bf16x8 a = *(const bf16x8*)&xA[mt * 16 + col][kq];
#pragma unroll
    for (int nt = 0; nt < 10; ++nt) {
      bf16x8 bw = *(const bf16x8*)(wqT + (size_t)(n0 + nt * 16 + col) * 640 + k0 + kq);
      acc[nt] = MFMA16(a, bw, acc[nt]);
    }
  }
#pragma unroll
  for (int nt = 0; nt < 10; ++nt) {
    int i = n0 + nt * 16 + col;
#pragma unroll
    for (int r = 0; r < 4; ++r) {
      int m = m0 + mt * 16 + quad * 4 + r;
      q[(size_t)m * 640 + i] = f2bf(acc[nt][r]);
    }
  }
}

// ================= K2: attention (QK^T -> softmax -> PV), av overwrites q =================
// grid 1024 (= 16 b * 64 s-tiles of 64), block 256; waves fully independent (wave = m-tile)
__global__ __launch_bounds__(256) void k_attn(short* qav,
                                              const short* __restrict__ kb,
                                              const short* __restrict__ vb) {
  int b = blockIdx.x >> 6;
  int s0 = (blockIdx.x & 63) * 64;
  int wave = threadIdx.x >> 6, lane = threadIdx.x & 63;
  int col = lane & 15, quad = lane >> 4, kq = quad * 8;
  __shared__ short pbuf[2][64][104];
  int mloc0 = wave * 16;
  // zero the t = 80..95 pad region of my wave's rows (once; never dirtied)
#pragma unroll
  for (int h = 0; h < 2; ++h)
#pragma unroll
    for (int i = 0; i < 4; ++i)
      pbuf[h][mloc0 + (lane >> 2)][80 + (lane & 3) * 4 + i] = 0;

  size_t qrow = (size_t)(b * SS + s0 + mloc0 + col) * 640;
#pragma unroll 1
  for (int pair = 0; pair < 4; ++pair) {
    f32x4 sc[2][5] = {};
#pragma unroll
    for (int ks = 0; ks < 3; ++ks) {
      int kk = ks * 32 + kq;  // d offset 0..95 (>=80 hits kb zero-pad)
      bf16x8 aq[2];
      aq[0] = *(const bf16x8*)(qav + qrow + (size_t)(pair * 2 + 0) * 80 + kk);
      aq[1] = *(const bf16x8*)(qav + qrow + (size_t)(pair * 2 + 1) * 80 + kk);
#pragma unroll
      for (int h = 0; h < 2; ++h) {
        const short* kbase = kb + (size_t)(b * NHH + pair * 2 + h) * 80 * DP;
#pragma unroll
        for (int tt = 0; tt < 5; ++tt) {
          bf16x8 bk = *(const bf16x8*)(kbase + (size_t)(tt * 16 + col) * DP + kk);
          sc[h][tt] = MFMA16(aq[h], bk, sc[h][tt]);
        }
      }
    }
    // softmax over t (rows handled per lane: row = quad*4 + r)
    float l[2][4];
#pragma unroll
    for (int h = 0; h < 2; ++h)
#pragma unroll
      for (int r = 0; r < 4; ++r) {
        float mx = -1e30f;
#pragma unroll
        for (int tt = 0; tt < 5; ++tt) {
          float v = sc[h][tt][r];
          if (tt == 4 && col >= 13) v = -1e30f;  // t = 77..79 masked
          sc[h][tt][r] = v;
          mx = fmaxf(mx, v);
        }
#pragma unroll
        for (int d = 1; d < 16; d <<= 1) mx = fmaxf(mx, __shfl_xor(mx, d));
        float sum = 0.f;
#pragma unroll
        for (int tt = 0; tt < 5; ++tt) {
          float e = __expf(sc[h][tt][r] - mx);
          sc[h][tt][r] = e;
          sum += e;
        }
#pragma unroll
        for (int d = 1; d < 16; d <<= 1) sum += __shfl_xor(sum, d);
        l[h][r] = sum;
      }
    // P -> LDS (C-layout -> A-layout transform), unnormalized exp
#pragma unroll
    for (int h = 0; h < 2; ++h)
#pragma unroll
      for (int tt = 0; tt < 5; ++tt)
#pragma unroll
        for (int r = 0; r < 4; ++r)
          pbuf[h][mloc0 + quad * 4 + r][tt * 16 + col] = f2bf(sc[h][tt][r]);
    // PV
    f32x4 av[2][5] = {};
#pragma unroll
    for (int ks = 0; ks < 3; ++ks) {
      int kk = ks * 32 + kq;  // t offset
      bf16x8 ap[2];
      ap[0] = *(const bf16x8*)&pbuf[0][mloc0 + col][kk];
      ap[1] = *(const bf16x8*)&pbuf[1][mloc0 + col][kk];
#pragma unroll
      for (int h = 0; h < 2; ++h) {
        const short* vbase = vb + (size_t)(b * NHH + pair * 2 + h) * 80 * DP;
#pragma unroll
        for (int dt = 0; dt < 5; ++dt) {
          bf16x8 bv = *(const bf16x8*)(vbase + (size_t)(dt * 16 + col) * DP + kk);
          av[h][dt] = MFMA16(ap[h], bv, av[h][dt]);
        }
      }
    }
    // divide by softmax denom, store in place of q
#pragma unroll
    for (int h = 0; h < 2; ++h) {
      float rl[4];
#pragma unroll
      for (int r = 0; r < 4; ++r) rl[r] = 1.f / l[h][r];
#pragma unroll
      for (int dt = 0; dt < 5; ++dt)
#pragma unroll
        for (int r = 0; r < 4; ++r) {
          int m = b * SS + s0 + mloc0 + quad * 4 + r;
          int i = (pair * 2 + h) * 80 + dt * 16 + col;
          qav[(size_t)m * 640 + i] = f2bf(av[h][dt][r] * rl[r]);
        }
    }
  }
}

// ================= K3: out projection + bias + residual =================
// grid (2 n-halves, 1024 m-blocks), block 512 (wave = (mt 0..3, nh 0..1))
__global__ __launch_bounds__(512) void k_out(const short* __restrict__ av,
                                             const short* __restrict__ woT,
                                             const float* __restrict__ bo,
                                             const float* __restrict__ hs,
                                             float* __restrict__ out) {
  int m0 = blockIdx.y * 64;
  int b = blockIdx.y >> 6;
  int s0 = (blockIdx.y & 63) * 64;
  int wave = threadIdx.x >> 6, lane = threadIdx.x & 63;
  int col = lane & 15, quad = lane >> 4, kq = quad * 8;
  int mt = wave & 3, nh = wave >> 2;
  int n0 = blockIdx.x * 320;
  __shared__ float obuf[160][65];
  f32x4 acc[10] = {};
  const bf16x8* Ab = (const bf16x8*)(av + (size_t)(m0 + mt * 16 + col) * 640 + kq);
  for (int k0 = 0; k0 < 640; k0 += 32) {
    bf16x8 a = Ab[k0 >> 3];
#pragma unroll
    for (int nt = 0; nt < 10; ++nt) {
      bf16x8 bw = *(const bf16x8*)(woT + (size_t)(n0 + nh * 160 + nt * 16 + col) * 640 + k0 + kq);
      acc[nt] = MFMA16(a, bw, acc[nt]);
    }
  }
  int cl = threadIdx.x & 63, rg = threadIdx.x >> 6;
#pragma unroll 1
  for (int phase = 0; phase < 2; ++phase) {
    if (nh == phase) {
#pragma unroll
      for (int nt = 0; nt < 10; ++nt)
#pragma unroll
        for (int r = 0; r < 4; ++r)
          obuf[nt * 16 + col][mt * 16 + quad * 4 + r] = acc[nt][r];
    }
    __syncthreads();
    for (int it = 0; it < 20; ++it) {
      int row = it * 8 + rg;
      int c = n0 + phase * 160 + row;
      size_t gidx = ((size_t)(b * CC + c)) * SS + s0 + cl;
      out[gidx] = obuf[row][cl] + bo[c] + hs[gidx];
    }
    __syncthreads();
  }
}

// ================= host =================
extern "C" void kernel_launch(void* const* d_in, const int* in_sizes, int n_in,
                              void* d_out, int out_size, void* d_ws, size_t ws_size,
                              hipStream_t stream) {
  const float* hs  = (const float*)d_in[0];
  const float* enc = (const float*)d_in[1];
  const float* lnw = (const float*)d_in[2];
  const float* lnb = (const float*)d_in[3];
  const float* wq  = (const float*)d_in[4];
  const float* wk  = (const float*)d_in[5];
  const float* wv  = (const float*)d_in[6];
  const float* wo  = (const float*)d_in[7];
  const float* bo  = (const float*)d_in[8];
  float* out = (float*)d_out;

  char* ws = (char*)d_ws;
  // ws layout (bytes):
  //   wqT    [640][640] bf16 :       0 ..   819200
  //   woT    [640][640] bf16 :  819200 ..  1638400
  //   kb  [16][8][80][96] bf16: 1638400 .. 3604480
  //   vb  [16][8][80][96] bf16: 3604480 .. 5570560
  //   muA [65536] f32        : 5570560 .. 5832704
  //   rsA [65536] f32        : 5832704 .. 6094848
  //   q/av [65536][640] bf16 : 6094848 .. 89980928 (+256 slack)
  short* wqT = (short*)(ws + 0);
  short* woT = (short*)(ws + 819200);
  short* kb  = (short*)(ws + 1638400);
  short* vb  = (short*)(ws + 3604480);
  float* muA = (float*)(ws + 5570560);
  float* rsA = (float*)(ws + 5832704);
  short* q   = (short*)(ws + 6094848);

  // zero kb+vb (d/t pad regions must be 0; rest overwritten)
  hipMemsetAsync(ws + 1638400, 0, 3932160, stream);

  k_wt<<<dim3(10, 10, 2), 256, 0, stream>>>(wq, wo, wqT, woT);
  k_stats<<<2048, 256, 0, stream>>>(hs, muA, rsA);
  k_kv<<<dim3(4, 2, 16), 320, 0, stream>>>(enc, wk, wv, kb, vb);
  k_qgemm<<<dim3(2, 1024), 512, 0, stream>>>(hs, muA, rsA, lnw, lnb, wqT, q);
  k_attn<<<1024, 256, 0, stream>>>(q, kb, vb);
  k_out<<<dim3(2, 1024), 512, 0, stream>>>(q, woT, bo, hs, out);
}

// Round 2
// 900.365 us; speedup vs baseline: 1.6856x; 1.6856x over previous
//
#include <hip/hip_runtime.h>

typedef short bf16x8 __attribute__((ext_vector_type(8)));
typedef float f32x4 __attribute__((ext_vector_type(4)));

#define MFMA16(a, b, c) __builtin_amdgcn_mfma_f32_16x16x32_bf16(a, b, c, 0, 0, 0)

__device__ __forceinline__ short f2bf(float x) {
  unsigned u = __builtin_bit_cast(unsigned, x);
  u += 0x7fffu + ((u >> 16) & 1u);
  return (short)(u >> 16);
}

// async global->LDS, 16B per lane; LDS dest must be wave-uniform base (HW adds lane*16)
__device__ __forceinline__ void gload16(const void* g, void* l) {
  __builtin_amdgcn_global_load_lds((const __attribute__((address_space(1))) void*)g,
                                   (__attribute__((address_space(3))) void*)l, 16, 0, 0);
}

// ---- problem constants ----
#define BB 16
#define SS 4096
#define CC 640
#define TT 77
#define NHH 8
#define HDD 80
#define DP 96
#define MM (BB * SS)

// ================= K0a: weight transpose + bf16 convert =================
__global__ __launch_bounds__(256) void k_wt(const float* __restrict__ wq,
                                            const float* __restrict__ wo,
                                            short* __restrict__ wqT,
                                            short* __restrict__ woT) {
  const float* src = blockIdx.z ? wo : wq;
  short* dst = blockIdx.z ? woT : wqT;
  int o0 = blockIdx.x * 64;
  int r0 = blockIdx.y * 64;
  __shared__ float t[64][65];
  int tx = threadIdx.x & 63, ty = threadIdx.x >> 6;
#pragma unroll
  for (int it = 0; it < 16; ++it) {
    int rr = it * 4 + ty;
    t[tx][rr] = src[(size_t)(r0 + rr) * 640 + o0 + tx];
  }
  __syncthreads();
#pragma unroll
  for (int it = 0; it < 16; ++it) {
    int orow = it * 4 + ty;
    dst[(size_t)(o0 + orow) * 640 + r0 + tx] = f2bf(t[orow][tx]);
  }
}

// ================= K0c: K/V projection (small) =================
__global__ __launch_bounds__(320) void k_kv(const float* __restrict__ enc,
                                            const float* __restrict__ wk,
                                            const float* __restrict__ wv,
                                            short* __restrict__ kb,
                                            short* __restrict__ vb) {
  int nq = blockIdx.x, kv = blockIdx.y, b = blockIdx.z;
  const float* w = kv ? wv : wk;
  int n0 = nq * 160;
  int wave = threadIdx.x >> 6, lane = threadIdx.x & 63;
  int col = lane & 15, quad = lane >> 4, kq = quad * 8;
  __shared__ short bT[160][40];
  f32x4 acc[10] = {};
  int t = wave * 16 + col;
  bool tv = (t < TT);
  const float* arow = enc + ((size_t)b * TT + (tv ? t : 0)) * 768;
  for (int x0 = 0; x0 < 768; x0 += 32) {
    __syncthreads();
    for (int idx = threadIdx.x; idx < 160 * 32; idx += 320) {
      int cc = idx % 160;
      int xx = idx / 160;
      bT[cc][xx] = f2bf(w[(size_t)(x0 + xx) * 640 + n0 + cc]);
    }
    __syncthreads();
    bf16x8 af = {};
    if (tv) {
      const float* ap = arow + x0 + kq;
      float4 a0 = *(const float4*)ap;
      float4 a1 = *(const float4*)(ap + 4);
      af[0] = f2bf(a0.x); af[1] = f2bf(a0.y); af[2] = f2bf(a0.z); af[3] = f2bf(a0.w);
      af[4] = f2bf(a1.x); af[5] = f2bf(a1.y); af[6] = f2bf(a1.z); af[7] = f2bf(a1.w);
    }
#pragma unroll
    for (int nt = 0; nt < 10; ++nt) {
      bf16x8 bw = *(const bf16x8*)&bT[nt * 16 + col][kq];
      acc[nt] = MFMA16(af, bw, acc[nt]);
    }
  }
  float scale = kv ? 1.f : 0.11180339887498949f;
#pragma unroll
  for (int nt = 0; nt < 10; ++nt) {
    int i = n0 + nt * 16 + col;
    int h = i / 80, d = i % 80;
#pragma unroll
    for (int r = 0; r < 4; ++r) {
      int trow = wave * 16 + quad * 4 + r;
      float v = acc[nt][r] * scale;
      if (kv)
        vb[(((size_t)(b * NHH + h) * 80 + d) * DP) + trow] = f2bf(v);
      else
        kb[(((size_t)(b * NHH + h) * 80 + trow) * DP) + d] = f2bf(v);
    }
  }
}

// ================= K1: fused LN stats + transform + transpose =================
// grid 1024 (16 b x 64 s-tiles of 64), block 256. out: xn[b*4096+s][c] bf16
__global__ __launch_bounds__(256) void k_ln(const float* __restrict__ hs,
                                            const float* __restrict__ lnw,
                                            const float* __restrict__ lnb,
                                            short* __restrict__ xn) {
  int b = blockIdx.x >> 6;
  int s0 = (blockIdx.x & 63) * 64;
  int sl = threadIdx.x & 63, cg = threadIdx.x >> 6;  // cg uniform per wave
  const float* base = hs + (size_t)b * CC * SS + s0 + sl;
  float sum = 0.f, sq = 0.f;
  for (int i = 0; i < 160; ++i) {
    int c = cg * 160 + i;
    float v = base[(size_t)c * SS];
    sum += v;
    sq += v * v;
  }
  __shared__ float red[2][4][64];
  __shared__ float smu[64], srs[64];
  red[0][cg][sl] = sum;
  red[1][cg][sl] = sq;
  __syncthreads();
  if (threadIdx.x < 64) {
    float s = 0.f, q = 0.f;
#pragma unroll
    for (int g = 0; g < 4; ++g) { s += red[0][g][threadIdx.x]; q += red[1][g][threadIdx.x]; }
    float mu = s * (1.f / 640.f);
    float var = q * (1.f / 640.f) - mu * mu;
    smu[threadIdx.x] = mu;
    srs[threadIdx.x] = rsqrtf(var + 1e-6f);
  }
  __syncthreads();
  float mu = smu[sl], rs = srs[sl];
  __shared__ short t[64][66];
  int l2 = threadIdx.x & 31, rg = threadIdx.x >> 5;
#pragma unroll 1
  for (int c0 = 0; c0 < 640; c0 += 64) {
    if (c0) __syncthreads();
#pragma unroll
    for (int j = 0; j < 16; ++j) {
      int cc = cg * 16 + j;
      int c = c0 + cc;
      float v = base[(size_t)c * SS];
      t[sl][cc] = f2bf((v - mu) * rs * lnw[c] + lnb[c]);
    }
    __syncthreads();
#pragma unroll
    for (int j = 0; j < 8; ++j) {
      int srow = j * 8 + rg;
      unsigned v = *(const unsigned*)&t[srow][l2 * 2];
      *(unsigned*)(xn + (size_t)(b * SS + s0 + srow) * 640 + c0 + l2 * 2) = v;
    }
  }
}

// ================= K2: Q projection, m97-style =================
// grid (512 s-tiles, 5 n-tiles), block 256 (4 waves 2x2). q[s][i] = xn[s][:] @ wqT[i][:]
__global__ __launch_bounds__(256) void k_q(const short* __restrict__ xn,
                                           const short* __restrict__ wqT,
                                           short* __restrict__ q) {
  int s0 = blockIdx.x * 128;
  int n0 = blockIdx.y * 128;
  __shared__ short sA[128 * 32];
  __shared__ short sB[128 * 32];
  int w = threadIdx.x >> 6, lane = threadIdx.x & 63;
  int col = lane & 15, quad = lane >> 4;
  int wm = w & 1, wn = w >> 1;
  int ldrow = lane >> 2;
  int ldoff = (lane & 3) * 8;
  const short* gA0 = xn + (size_t)(s0 + w * 32 + ldrow) * 640 + ldoff;
  const short* gA1 = gA0 + 16 * 640;
  const short* gB0 = wqT + (size_t)(n0 + w * 32 + ldrow) * 640 + ldoff;
  const short* gB1 = gB0 + 16 * 640;
  short* lA0 = sA + (w * 32) * 32;  // wave-uniform
  short* lA1 = lA0 + 16 * 32;
  short* lB0 = sB + (w * 32) * 32;
  short* lB1 = lB0 + 16 * 32;
  f32x4 acc[4][4] = {};
  for (int k0 = 0; k0 < 640; k0 += 32) {
    __syncthreads();
    gload16(gA0 + k0, lA0);
    gload16(gA1 + k0, lA1);
    gload16(gB0 + k0, lB0);
    gload16(gB1 + k0, lB1);
    __syncthreads();
    bf16x8 a[4], bb[4];
#pragma unroll
    for (int mt = 0; mt < 4; ++mt)
      a[mt] = *(const bf16x8*)(sA + (wm * 64 + mt * 16 + col) * 32 + quad * 8);
#pragma unroll
    for (int nt = 0; nt < 4; ++nt)
      bb[nt] = *(const bf16x8*)(sB + (wn * 64 + nt * 16 + col) * 32 + quad * 8);
#pragma unroll
    for (int mt = 0; mt < 4; ++mt)
#pragma unroll
      for (int nt = 0; nt < 4; ++nt)
        acc[mt][nt] = MFMA16(a[mt], bb[nt], acc[mt][nt]);
  }
#pragma unroll
  for (int mt = 0; mt < 4; ++mt)
#pragma unroll
    for (int nt = 0; nt < 4; ++nt) {
      int i = n0 + wn * 64 + nt * 16 + col;
#pragma unroll
      for (int r = 0; r < 4; ++r) {
        int s = s0 + wm * 64 + mt * 16 + quad * 4 + r;
        q[(size_t)s * 640 + i] = f2bf(acc[mt][nt][r]);
      }
    }
}

// ================= K3: attention (QK^T -> softmax -> PV), av overwrites q =================
__global__ __launch_bounds__(256) void k_attn(short* qav,
                                              const short* __restrict__ kb,
                                              const short* __restrict__ vb) {
  int b = blockIdx.x >> 6;
  int s0 = (blockIdx.x & 63) * 64;
  int wave = threadIdx.x >> 6, lane = threadIdx.x & 63;
  int col = lane & 15, quad = lane >> 4, kq = quad * 8;
  __shared__ short pbuf[2][64][104];
  int mloc0 = wave * 16;
#pragma unroll
  for (int h = 0; h < 2; ++h)
#pragma unroll
    for (int i = 0; i < 4; ++i)
      pbuf[h][mloc0 + (lane >> 2)][80 + (lane & 3) * 4 + i] = 0;

  size_t qrow = (size_t)(b * SS + s0 + mloc0 + col) * 640;
#pragma unroll 1
  for (int pair = 0; pair < 4; ++pair) {
    f32x4 sc[2][5] = {};
#pragma unroll
    for (int ks = 0; ks < 3; ++ks) {
      int kk = ks * 32 + kq;
      bf16x8 aq[2];
      aq[0] = *(const bf16x8*)(qav + qrow + (size_t)(pair * 2 + 0) * 80 + kk);
      aq[1] = *(const bf16x8*)(qav + qrow + (size_t)(pair * 2 + 1) * 80 + kk);
#pragma unroll
      for (int h = 0; h < 2; ++h) {
        const short* kbase = kb + (size_t)(b * NHH + pair * 2 + h) * 80 * DP;
#pragma unroll
        for (int tt = 0; tt < 5; ++tt) {
          bf16x8 bk = *(const bf16x8*)(kbase + (size_t)(tt * 16 + col) * DP + kk);
          sc[h][tt] = MFMA16(aq[h], bk, sc[h][tt]);
        }
      }
    }
    float l[2][4];
#pragma unroll
    for (int h = 0; h < 2; ++h)
#pragma unroll
      for (int r = 0; r < 4; ++r) {
        float mx = -1e30f;
#pragma unroll
        for (int tt = 0; tt < 5; ++tt) {
          float v = sc[h][tt][r];
          if (tt == 4 && col >= 13) v = -1e30f;
          sc[h][tt][r] = v;
          mx = fmaxf(mx, v);
        }
#pragma unroll
        for (int d = 1; d < 16; d <<= 1) mx = fmaxf(mx, __shfl_xor(mx, d));
        float sum = 0.f;
#pragma unroll
        for (int tt = 0; tt < 5; ++tt) {
          float e = __expf(sc[h][tt][r] - mx);
          sc[h][tt][r] = e;
          sum += e;
        }
#pragma unroll
        for (int d = 1; d < 16; d <<= 1) sum += __shfl_xor(sum, d);
        l[h][r] = sum;
      }
#pragma unroll
    for (int h = 0; h < 2; ++h)
#pragma unroll
      for (int tt = 0; tt < 5; ++tt)
#pragma unroll
        for (int r = 0; r < 4; ++r)
          pbuf[h][mloc0 + quad * 4 + r][tt * 16 + col] = f2bf(sc[h][tt][r]);
    f32x4 av[2][5] = {};
#pragma unroll
    for (int ks = 0; ks < 3; ++ks) {
      int kk = ks * 32 + kq;
      bf16x8 ap[2];
      ap[0] = *(const bf16x8*)&pbuf[0][mloc0 + col][kk];
      ap[1] = *(const bf16x8*)&pbuf[1][mloc0 + col][kk];
#pragma unroll
      for (int h = 0; h < 2; ++h) {
        const short* vbase = vb + (size_t)(b * NHH + pair * 2 + h) * 80 * DP;
#pragma unroll
        for (int dt = 0; dt < 5; ++dt) {
          bf16x8 bv = *(const bf16x8*)(vbase + (size_t)(dt * 16 + col) * DP + kk);
          av[h][dt] = MFMA16(ap[h], bv, av[h][dt]);
        }
      }
    }
#pragma unroll
    for (int h = 0; h < 2; ++h) {
      float rl[4];
#pragma unroll
      for (int r = 0; r < 4; ++r) rl[r] = 1.f / l[h][r];
#pragma unroll
      for (int dt = 0; dt < 5; ++dt)
#pragma unroll
        for (int r = 0; r < 4; ++r) {
          int m = b * SS + s0 + mloc0 + quad * 4 + r;
          int i = (pair * 2 + h) * 80 + dt * 16 + col;
          qav[(size_t)m * 640 + i] = f2bf(av[h][dt][r] * rl[r]);
        }
    }
  }
}

// ================= K4: out projection + bias + residual, m97-style =================
// grid (512 s-tiles, 5 c-tiles), block 256. A = woT (M=c), B = av (N=s)
// out[b][c][s] = sum_i woT[c][i]*av[s][i] + bo[c] + hs[b][c][s]
__global__ __launch_bounds__(256) void k_o(const short* __restrict__ av,
                                           const short* __restrict__ woT,
                                           const float* __restrict__ bo,
                                           const float* __restrict__ hs,
                                           float* __restrict__ out) {
  int s0 = blockIdx.x * 128;  // global s (= b*4096 + sin)
  int c0 = blockIdx.y * 128;
  __shared__ short sA[128 * 32];
  __shared__ short sB[128 * 32];
  int w = threadIdx.x >> 6, lane = threadIdx.x & 63;
  int col = lane & 15, quad = lane >> 4;
  int wm = w & 1, wn = w >> 1;
  int ldrow = lane >> 2;
  int ldoff = (lane & 3) * 8;
  const short* gA0 = woT + (size_t)(c0 + w * 32 + ldrow) * 640 + ldoff;
  const short* gA1 = gA0 + 16 * 640;
  const short* gB0 = av + (size_t)(s0 + w * 32 + ldrow) * 640 + ldoff;
  const short* gB1 = gB0 + 16 * 640;
  short* lA0 = sA + (w * 32) * 32;
  short* lA1 = lA0 + 16 * 32;
  short* lB0 = sB + (w * 32) * 32;
  short* lB1 = lB0 + 16 * 32;
  f32x4 acc[4][4] = {};
  for (int k0 = 0; k0 < 640; k0 += 32) {
    __syncthreads();
    gload16(gA0 + k0, lA0);
    gload16(gA1 + k0, lA1);
    gload16(gB0 + k0, lB0);
    gload16(gB1 + k0, lB1);
    __syncthreads();
    bf16x8 a[4], bb[4];
#pragma unroll
    for (int mt = 0; mt < 4; ++mt)
      a[mt] = *(const bf16x8*)(sA + (wm * 64 + mt * 16 + col) * 32 + quad * 8);
#pragma unroll
    for (int nt = 0; nt < 4; ++nt)
      bb[nt] = *(const bf16x8*)(sB + (wn * 64 + nt * 16 + col) * 32 + quad * 8);
#pragma unroll
    for (int mt = 0; mt < 4; ++mt)
#pragma unroll
      for (int nt = 0; nt < 4; ++nt)
        acc[mt][nt] = MFMA16(a[mt], bb[nt], acc[mt][nt]);
  }
  int b = s0 >> 12;
  int sin = s0 & 4095;
  size_t obase = (size_t)b * CC * SS;
#pragma unroll
  for (int mt = 0; mt < 4; ++mt)
#pragma unroll
    for (int nt = 0; nt < 4; ++nt) {
      int c = c0 + wm * 64 + mt * 16 + quad * 4;
      int s = sin + wn * 64 + nt * 16 + col;
#pragma unroll
      for (int r = 0; r < 4; ++r) {
        size_t idx = obase + (size_t)(c + r) * SS + s;
        out[idx] = acc[mt][nt][r] + bo[c + r] + hs[idx];
      }
    }
}

// ================= host =================
extern "C" void kernel_launch(void* const* d_in, const int* in_sizes, int n_in,
                              void* d_out, int out_size, void* d_ws, size_t ws_size,
                              hipStream_t stream) {
  const float* hs  = (const float*)d_in[0];
  const float* enc = (const float*)d_in[1];
  const float* lnw = (const float*)d_in[2];
  const float* lnb = (const float*)d_in[3];
  const float* wq  = (const float*)d_in[4];
  const float* wk  = (const float*)d_in[5];
  const float* wv  = (const float*)d_in[6];
  const float* wo  = (const float*)d_in[7];
  const float* bo  = (const float*)d_in[8];
  float* out = (float*)d_out;

  char* ws = (char*)d_ws;
  // ws layout (bytes):
  //   wqT [640][640] bf16   :        0 ..   819200
  //   woT [640][640] bf16   :   819200 ..  1638400
  //   kb  [16][8][80][96]   :  1638400 ..  3604480
  //   vb  [16][8][80][96]   :  3604480 ..  5570560
  //   xn  [65536][640] bf16 :  5570560 .. 89456640
  //   q/av[65536][640] bf16 : 89456640 .. 173342720
  short* wqT = (short*)(ws + 0);
  short* woT = (short*)(ws + 819200);
  short* kb  = (short*)(ws + 1638400);
  short* vb  = (short*)(ws + 3604480);
  short* xn  = (short*)(ws + 5570560);
  short* q   = (short*)(ws + 89456640);

  hipMemsetAsync(ws + 1638400, 0, 3932160, stream);  // kb/vb pad regions

  k_wt<<<dim3(10, 10, 2), 256, 0, stream>>>(wq, wo, wqT, woT);
  k_kv<<<dim3(4, 2, 16), 320, 0, stream>>>(enc, wk, wv, kb, vb);
  k_ln<<<1024, 256, 0, stream>>>(hs, lnw, lnb, xn);
  k_q<<<dim3(512, 5), 256, 0, stream>>>(xn, wqT, q);
  k_attn<<<1024, 256, 0, stream>>>(q, kb, vb);
  k_o<<<dim3(512, 5), 256, 0, stream>>>(q, woT, bo, hs, out);
}